// Round 1
// baseline (355.115 us; speedup 1.0000x reference)
//
#include <hip/hip_runtime.h>

#define BB 4
#define TT 2048
#define CC 1024
#define HH 16
#define DHH 64
#define KK 1024   // GEMM K dim (= CC)

typedef __attribute__((ext_vector_type(4))) float f32x4;
typedef __attribute__((ext_vector_type(8))) short bf16x8;
typedef __attribute__((ext_vector_type(4))) unsigned short us4;
typedef __attribute__((ext_vector_type(2))) unsigned int u32x2;

#define MFMA(a, b, c) __builtin_amdgcn_mfma_f32_16x16x32_bf16((a), (b), (c), 0, 0, 0)

typedef const __attribute__((address_space(1))) unsigned int* gas_t;
typedef __attribute__((address_space(3))) unsigned int* las_t;
__device__ __forceinline__ void gload16(const unsigned short* g, unsigned short* l) {
  // async global->LDS, 16B/lane; LDS dest = wave-uniform base + lane*16
  __builtin_amdgcn_global_load_lds((gas_t)g, (las_t)l, 16, 0, 0);
}

__device__ __forceinline__ unsigned short f2bf(float x) {
  unsigned u = __builtin_bit_cast(unsigned, x);
  u += 0x7FFF + ((u >> 16) & 1);   // RNE; finite inputs
  return (unsigned short)(u >> 16);
}
__device__ __forceinline__ float bf2f(unsigned short h) {
  unsigned u = ((unsigned)h) << 16;
  return __builtin_bit_cast(float, u);
}

#if __has_builtin(__builtin_amdgcn_cvt_pk_bf16_f32)
__device__ __forceinline__ unsigned pack2bf(float a, float b) {
  auto v = __builtin_amdgcn_cvt_pk_bf16_f32(a, b);   // v_cvt_pk_bf16_f32 (gfx950)
  return __builtin_bit_cast(unsigned, v);
}
#else
__device__ __forceinline__ unsigned pack2bf(float a, float b) {
  return (unsigned)f2bf(a) | ((unsigned)f2bf(b) << 16);
}
#endif

// fused weight transpose+convert: y in {0,1,2}: [16,1024,64]->[16,64,1024]
//                                 y == 3     : [1024,1024]->[1024,1024]^T
__global__ void convW_kernel(const float* __restrict__ Wq, const float* __restrict__ Wk,
                             const float* __restrict__ Wv, const float* __restrict__ Wo,
                             unsigned short* __restrict__ WqT, unsigned short* __restrict__ WkT,
                             unsigned short* __restrict__ WvT, unsigned short* __restrict__ WoT) {
  int y = blockIdx.y;
  const float* in = (y == 0) ? Wq : (y == 1) ? Wk : (y == 2) ? Wv : Wo;
  unsigned short* out = (y == 0) ? WqT : (y == 1) ? WkT : (y == 2) ? WvT : WoT;
  int R = 1024, S = (y < 3) ? 64 : 1024;
  int i = blockIdx.x * 256 + threadIdx.x;
  int g = (y < 3) ? (i >> 16) : 0;
  int rs = (y < 3) ? (i & 65535) : i;
  int r = rs / S, s = rs % S;
  long base = (long)g * R * S;
  out[base + (long)s * R + r] = f2bf(in[base + rs]);
}

// fused elementwise f32 -> bf16 for q,k,v
__global__ void convX3_kernel(const float* __restrict__ q, const float* __restrict__ k,
                              const float* __restrict__ v, unsigned short* __restrict__ Xq,
                              unsigned short* __restrict__ Xk, unsigned short* __restrict__ Xv) {
  int y = blockIdx.y;
  const float* in = (y == 0) ? q : (y == 1) ? k : v;
  unsigned short* out = (y == 0) ? Xq : (y == 1) ? Xk : Xv;
  int i = (blockIdx.x * 256 + threadIdx.x) * 4;
  f32x4 x = *(const f32x4*)(in + i);
  us4 o;
  o[0] = f2bf(x[0]); o[1] = f2bf(x[1]); o[2] = f2bf(x[2]); o[3] = f2bf(x[3]);
  *(us4*)(out + i) = o;
}

// ---- shared GEMM core (m97 structure): 128x128 C-tile, BK=32, 4 waves 2x2 ----
// SWAP_=1 computes the transposed product (A-operand <- B tile) for V.
#define GEMM_CORE(A_, B_, m0_, n0_, SWAP_)                                              \
  __shared__ __align__(16) unsigned short als[128 * 32];                                \
  __shared__ __align__(16) unsigned short bls[128 * 32];                                \
  int w = threadIdx.x >> 6, lane = threadIdx.x & 63;                                    \
  int quad = lane >> 4, mr = lane & 15;                                                 \
  int wm = w & 1, wn = w >> 1;                                                          \
  int sr = w * 16 + (lane >> 2);                                                        \
  int kofs = (((lane & 3) ^ ((sr >> 1) & 3)) << 3);                                     \
  const unsigned short* agp = (A_) + (long)((m0_) + sr) * KK + kofs;                    \
  const unsigned short* bgp = (B_) + (long)((n0_) + sr) * KK + kofs;                    \
  unsigned short* alu = als + w * 16 * 32;                                              \
  unsigned short* blu = bls + w * 16 * 32;                                              \
  const unsigned short* aL[4]; const unsigned short* bL[4];                             \
  _Pragma("unroll") for (int i = 0; i < 4; ++i) {                                       \
    int ar = wm * 64 + i * 16 + mr;                                                     \
    aL[i] = als + ar * 32 + ((quad ^ ((ar >> 1) & 3)) << 3);                            \
    int br = wn * 64 + i * 16 + mr;                                                     \
    bL[i] = bls + br * 32 + ((quad ^ ((br >> 1) & 3)) << 3);                            \
  }                                                                                     \
  f32x4 acc[4][4] = {};                                                                 \
  for (int k0 = 0; k0 < KK; k0 += 32) {                                                 \
    __syncthreads();                                                                    \
    gload16(agp + k0, alu);                                                             \
    gload16(agp + (long)64 * KK + k0, alu + 64 * 32);                                   \
    gload16(bgp + k0, blu);                                                             \
    gload16(bgp + (long)64 * KK + k0, blu + 64 * 32);                                   \
    __syncthreads();                                                                    \
    bf16x8 af[4], bf[4];                                                                \
    _Pragma("unroll") for (int i = 0; i < 4; ++i) af[i] = *(const bf16x8*)aL[i];        \
    _Pragma("unroll") for (int i = 0; i < 4; ++i) bf[i] = *(const bf16x8*)bL[i];        \
    _Pragma("unroll") for (int mi = 0; mi < 4; ++mi)                                    \
      _Pragma("unroll") for (int ni = 0; ni < 4; ++ni)                                  \
        acc[mi][ni] = (SWAP_) ? MFMA(bf[ni], af[mi], acc[mi][ni])                       \
                              : MFMA(af[mi], bf[ni], acc[mi][ni]);                      \
  }

// Q/K projections: blockIdx.y selects; OUT [B,H,T,DH]
// Q gets pre-scaled by 0.125*log2(e) so attention can use exp2 directly.
__global__ __launch_bounds__(256) void projqk_kernel(
    const unsigned short* __restrict__ Xq, const unsigned short* __restrict__ Xk,
    const unsigned short* __restrict__ WqT, const unsigned short* __restrict__ WkT,
    unsigned short* __restrict__ qh, unsigned short* __restrict__ kh) {
  int y = blockIdx.y;
  const unsigned short* A = (y == 0) ? Xq : Xk;
  const unsigned short* Bw = (y == 0) ? WqT : WkT;
  unsigned short* OUT = (y == 0) ? qh : kh;
  float scale = (y == 0) ? 0.18033688011112043f : 1.0f;   // 0.125*log2(e)
  int m0 = (blockIdx.x >> 3) * 128, n0 = (blockIdx.x & 7) * 128;
  GEMM_CORE(A, Bw, m0, n0, 0)
#pragma unroll
  for (int mi = 0; mi < 4; ++mi)
#pragma unroll
    for (int ni = 0; ni < 4; ++ni) {
      int col = n0 + wn * 64 + ni * 16 + mr;
      int h = col >> 6, d = col & 63;
#pragma unroll
      for (int r = 0; r < 4; ++r) {
        int row = m0 + wm * 64 + mi * 16 + quad * 4 + r;
        int b = row >> 11, t = row & 2047;
        OUT[(((long)b * HH + h) * TT + t) * DHH + d] = f2bf(acc[mi][ni][r] * scale);
      }
    }
}

// V projection, transposed output: vh [B,H,DH,T]
__global__ __launch_bounds__(256) void projv_kernel(const unsigned short* __restrict__ Xv,
                                                    const unsigned short* __restrict__ WvT,
                                                    unsigned short* __restrict__ vh) {
  int m0 = (blockIdx.x >> 3) * 128, n0 = (blockIdx.x & 7) * 128;
  GEMM_CORE(Xv, WvT, m0, n0, 1)
#pragma unroll
  for (int mi = 0; mi < 4; ++mi)
#pragma unroll
    for (int ni = 0; ni < 4; ++ni) {
      int token = m0 + wm * 64 + mi * 16 + mr;
      int b = token >> 11, t = token & 2047;
#pragma unroll
      for (int r = 0; r < 4; ++r) {
        int c = n0 + wn * 64 + ni * 16 + quad * 4 + r;
        int h = c >> 6, dh = c & 63;
        vh[(((long)b * HH + h) * DHH + dh) * TT + t] = f2bf(acc[mi][ni][r]);
      }
    }
}

// output projection: C[8192][1024] f32 = A.WoT^T + bo
__global__ __launch_bounds__(256) void oproj_kernel(const unsigned short* __restrict__ A,
                                                    const unsigned short* __restrict__ WoT,
                                                    const float* __restrict__ bo,
                                                    float* __restrict__ OUT) {
  int m0 = (blockIdx.x >> 3) * 128, n0 = (blockIdx.x & 7) * 128;
  GEMM_CORE(A, WoT, m0, n0, 0)
#pragma unroll
  for (int mi = 0; mi < 4; ++mi)
#pragma unroll
    for (int ni = 0; ni < 4; ++ni) {
      int col = n0 + wn * 64 + ni * 16 + mr;
      float bias = bo[col];
#pragma unroll
      for (int r = 0; r < 4; ++r) {
        int row = m0 + wm * 64 + mi * 16 + quad * 4 + r;
        OUT[(long)row * 1024 + col] = acc[mi][ni][r] + bias;
      }
    }
}

// MFMA flash attention. QH/KH: [B,H,T,DH] ; VT: [B,H,DH,T] ; AO: [B,T,H*DH] bf16
// Q pre-scaled by 0.125*log2e -> p = exp2(S). Interior tiles skip masking.
// v2: K/V double-buffered (stage next tile at loop top, one __syncthreads per
//     tile -> staging latency hides under compute); kf/vf hoisted out of the
//     mi loop (each wave now reads the K and V LDS tile exactly once: LDS
//     b128 reads 36 -> 20 per wave-tile); setprio(1) around MFMA clusters.
__global__ __launch_bounds__(256) void attn_mfma_kernel(const unsigned short* __restrict__ QH,
                                                        const unsigned short* __restrict__ KH,
                                                        const unsigned short* __restrict__ VT,
                                                        unsigned short* __restrict__ AO) {
  __shared__ __align__(16) unsigned short kls[2][64 * 64];  // [s][d], chunk^=s&7
  __shared__ __align__(16) unsigned short vls[2][64 * 64];  // [d][s], chunk^=d&7
  __shared__ __align__(16) unsigned short pls[4 * 32 * 72]; // per wave [q][s+8]

  int w = threadIdx.x >> 6, lane = threadIdx.x & 63;
  int quad = lane >> 4, mr = lane & 15;
  int m7 = mr & 7;
  int bh = blockIdx.x & 63;            // qb-major: heavy tiles dispatch first
  int qb = 15 - (blockIdx.x >> 6);
  int q0 = qb * 128;
  int b = bh >> 4, h = bh & 15;

  const unsigned short* kbase = KH + (long)bh * TT * DHH;
  const unsigned short* vtb  = VT + (long)bh * DHH * TT;
  const unsigned short* qbp  = QH + (long)bh * TT * DHH;

  // Q fragments (MFMA B-operand for S^T): q = q0+w*32+mi*16+mr
  bf16x8 qf[2][2];
#pragma unroll
  for (int mi = 0; mi < 2; ++mi)
#pragma unroll
    for (int kd = 0; kd < 2; ++kd)
      qf[mi][kd] = *(const bf16x8*)(qbp + (long)(q0 + w * 32 + mi * 16 + mr) * DHH +
                                    kd * 32 + quad * 8);

  int srow = lane >> 3, schunk = lane & 7;
  const unsigned short* kgp = kbase + (long)(w * 16 + srow) * DHH + ((schunk ^ srow) << 3);
  const unsigned short* vgp = vtb + (long)(w * 16 + srow) * TT + ((schunk ^ srow) << 3);

  f32x4 O[2][4] = {};   // [mi][nd]  row=quad*4+r (q), col=mr (d)
  float lpart[2] = {};  // per-lane softmax denominator partials (q = mi*16+mr)
  unsigned short* pw = pls + w * 32 * 72;
  int qtop = q0 + w * 32;
  int send = q0 + 128;

  // prologue: stage tile 0 into buffer 0
  {
    unsigned short* klu = &kls[0][w * 16 * 64];
    unsigned short* vlu = &vls[0][w * 16 * 64];
    gload16(kgp, klu);
    gload16(kgp + 8 * DHH, klu + 8 * 64);
    gload16(vgp, vlu);
    gload16(vgp + 8 * TT, vlu + 8 * 64);
  }
  __syncthreads();

  for (int s0 = 0; s0 < send; s0 += 64) {
    int cur = (s0 >> 6) & 1;
    // issue next-tile staging first; its latency hides under this tile's compute
    if (s0 + 64 < send) {
      int nxt = cur ^ 1;
      unsigned short* klu = &kls[nxt][w * 16 * 64];
      unsigned short* vlu = &vls[nxt][w * 16 * 64];
      gload16(kgp + (long)(s0 + 64) * DHH, klu);
      gload16(kgp + (long)(s0 + 64) * DHH + 8 * DHH, klu + 8 * 64);
      gload16(vgp + (s0 + 64), vlu);
      gload16(vgp + (s0 + 64) + 8 * TT, vlu + 8 * 64);
    }
    const unsigned short* kT = &kls[cur][0];
    const unsigned short* vT = &vls[cur][0];

#pragma unroll
    for (int sk = 0; sk < 2; ++sk) {
      int kt0 = s0 + sk * 32;
      if (kt0 > qtop + 31) continue;       // wave-uniform: both mi masked
      // --- QK^T + exp2 for both mi, sharing the kf fragments ---
#pragma unroll
      for (int nh = 0; nh < 2; ++nh) {
        int ns = sk * 2 + nh;
        int krow = ns * 16 + mr;
        int p0 = quad ^ m7;
        bf16x8 kf0 = *(const bf16x8*)&kT[krow * 64 + p0 * 8];
        bf16x8 kf1 = *(const bf16x8*)&kT[krow * 64 + (p0 ^ 4) * 8];
#pragma unroll
        for (int mi = 0; mi < 2; ++mi) {
          int qmin = qtop + mi * 16;
          if (kt0 > qmin + 15) continue;   // wave-uniform
          int qcol = qmin + mr;
          bool full = (kt0 + 31 <= qmin);  // wave-uniform: no mask needed
          f32x4 acc = {};
          __builtin_amdgcn_s_setprio(1);
          acc = MFMA(kf0, qf[mi][0], acc);
          acc = MFMA(kf1, qf[mi][1], acc);
          __builtin_amdgcn_s_setprio(0);
          float pe0, pe1, pe2, pe3;
          if (full) {
            pe0 = __builtin_amdgcn_exp2f(acc[0]);
            pe1 = __builtin_amdgcn_exp2f(acc[1]);
            pe2 = __builtin_amdgcn_exp2f(acc[2]);
            pe3 = __builtin_amdgcn_exp2f(acc[3]);
          } else {
            int sbase = s0 + ns * 16 + quad * 4;
            pe0 = (sbase + 0 <= qcol) ? __builtin_amdgcn_exp2f(acc[0]) : 0.f;
            pe1 = (sbase + 1 <= qcol) ? __builtin_amdgcn_exp2f(acc[1]) : 0.f;
            pe2 = (sbase + 2 <= qcol) ? __builtin_amdgcn_exp2f(acc[2]) : 0.f;
            pe3 = (sbase + 3 <= qcol) ? __builtin_amdgcn_exp2f(acc[3]) : 0.f;
          }
          lpart[mi] += (pe0 + pe1) + (pe2 + pe3);
          u32x2 pk;
          pk[0] = pack2bf(pe0, pe1);
          pk[1] = pack2bf(pe2, pe3);
          *(u32x2*)&pw[(mi * 16 + mr) * 72 + ns * 16 + quad * 4] = pk;
        }
      }
      // --- O += P V  (A=P from pls, B=V^T from vls; same-wave LDS, no barrier)
      // vf hoisted over mi: each V fragment read once, used by both mi.
      bool act0 = (kt0 <= qtop + 15);      // wave-uniform; mi=1 always active here
      bf16x8 pf1 = *(const bf16x8*)&pw[(16 + mr) * 72 + sk * 32 + quad * 8];
      bf16x8 pf0;
      if (act0) pf0 = *(const bf16x8*)&pw[mr * 72 + sk * 32 + quad * 8];
      int pv = (sk * 4 + quad) ^ m7;
      __builtin_amdgcn_s_setprio(1);
#pragma unroll
      for (int nd = 0; nd < 4; ++nd) {
        bf16x8 vf = *(const bf16x8*)&vT[(nd * 16 + mr) * 64 + pv * 8];
        if (act0) O[0][nd] = MFMA(pf0, vf, O[0][nd]);
        O[1][nd] = MFMA(pf1, vf, O[1][nd]);
      }
      __builtin_amdgcn_s_setprio(0);
    }
    // one barrier per tile: drains this wave's next-tile gload (vmcnt 0) and
    // ensures all waves are done reading buf[cur] before it is re-staged.
    __syncthreads();
  }

  // reduce denominators across quads; lane holds 1/l for q = mi*16+mr
  float rl[2];
#pragma unroll
  for (int mi = 0; mi < 2; ++mi) {
    float s = lpart[mi];
    s += __shfl_xor(s, 16);
    s += __shfl_xor(s, 32);
    rl[mi] = 1.0f / s;
  }
#pragma unroll
  for (int mi = 0; mi < 2; ++mi) {
#pragma unroll
    for (int r = 0; r < 4; ++r) {
      float rlr = __shfl(rl[mi], (lane & 48) | (quad * 4 + r));
      int t = q0 + w * 32 + mi * 16 + quad * 4 + r;
      unsigned short* orow = AO + ((long)(b * TT + t)) * (HH * DHH) + h * DHH + mr;
#pragma unroll
      for (int nd = 0; nd < 4; ++nd)
        orow[nd * 16] = f2bf(O[mi][nd][r] * rlr);
    }
  }
}

extern "C" void kernel_launch(void* const* d_in, const int* in_sizes, int n_in,
                              void* d_out, int out_size, void* d_ws, size_t ws_size,
                              hipStream_t stream) {
  const float* k  = (const float*)d_in[0];
  const float* q  = (const float*)d_in[1];
  const float* v  = (const float*)d_in[2];
  const float* Wk = (const float*)d_in[3];
  const float* Wq = (const float*)d_in[4];
  const float* Wv = (const float*)d_in[5];
  const float* Wo = (const float*)d_in[6];
  const float* bo = (const float*)d_in[7];
  float* out = (float*)d_out;

  const size_t PROJ = (size_t)BB * HH * TT * DHH;  // 8.39M elems
  const size_t WSZ  = (size_t)HH * DHH * CC;       // 1.05M elems
  unsigned short* qh  = (unsigned short*)d_ws;
  unsigned short* kh  = qh + PROJ;
  unsigned short* vh  = kh + PROJ;                 // [B,H,DH,T] (transposed)
  unsigned short* WqT = vh + PROJ;
  unsigned short* WkT = WqT + WSZ;
  unsigned short* WvT = WkT + WSZ;
  unsigned short* WoT = WvT + WSZ;
  unsigned short* AO  = WoT + WSZ;                 // B*T*1024 bf16
  unsigned short* Xq  = AO;                        // alias: dead before attn writes AO
  unsigned short* Xk  = (unsigned short*)out;      // d_out doubles as bf16 scratch
  unsigned short* Xv  = Xk + PROJ;                 // (fully overwritten by oproj later)

  convW_kernel<<<dim3(4096, 4), 256, 0, stream>>>(Wq, Wk, Wv, Wo, WqT, WkT, WvT, WoT);
  convX3_kernel<<<dim3(8192, 3), 256, 0, stream>>>(q, k, v, Xq, Xk, Xv);
  projqk_kernel<<<dim3(512, 2), 256, 0, stream>>>(Xq, Xk, WqT, WkT, qh, kh);
  projv_kernel<<<512, 256, 0, stream>>>(Xv, WvT, vh);
  attn_mfma_kernel<<<BB * HH * (TT / 128), 256, 0, stream>>>(qh, kh, vh, AO);
  oproj_kernel<<<512, 256, 0, stream>>>(AO, WoT, bo, out);
}

// Round 2
// 338.346 us; speedup vs baseline: 1.0496x; 1.0496x over previous
//
#include <hip/hip_runtime.h>

#define BB 4
#define TT 2048
#define CC 1024
#define HH 16
#define DHH 64
#define KK 1024   // GEMM K dim (= CC)

typedef __attribute__((ext_vector_type(4))) float f32x4;
typedef __attribute__((ext_vector_type(8))) short bf16x8;
typedef __attribute__((ext_vector_type(4))) unsigned short us4;
typedef __attribute__((ext_vector_type(2))) unsigned int u32x2;

#define MFMA(a, b, c) __builtin_amdgcn_mfma_f32_16x16x32_bf16((a), (b), (c), 0, 0, 0)

typedef const __attribute__((address_space(1))) unsigned int* gas_t;
typedef __attribute__((address_space(3))) unsigned int* las_t;
__device__ __forceinline__ void gload16(const unsigned short* g, unsigned short* l) {
  // async global->LDS, 16B/lane; LDS dest = wave-uniform base + lane*16
  __builtin_amdgcn_global_load_lds((gas_t)g, (las_t)l, 16, 0, 0);
}

__device__ __forceinline__ unsigned short f2bf(float x) {
  unsigned u = __builtin_bit_cast(unsigned, x);
  u += 0x7FFF + ((u >> 16) & 1);   // RNE; finite inputs
  return (unsigned short)(u >> 16);
}
__device__ __forceinline__ float bf2f(unsigned short h) {
  unsigned u = ((unsigned)h) << 16;
  return __builtin_bit_cast(float, u);
}

#if __has_builtin(__builtin_amdgcn_cvt_pk_bf16_f32)
__device__ __forceinline__ unsigned pack2bf(float a, float b) {
  auto v = __builtin_amdgcn_cvt_pk_bf16_f32(a, b);   // v_cvt_pk_bf16_f32 (gfx950)
  return __builtin_bit_cast(unsigned, v);
}
#else
__device__ __forceinline__ unsigned pack2bf(float a, float b) {
  return (unsigned)f2bf(a) | ((unsigned)f2bf(b) << 16);
}
#endif

// fused conversion pass: one launch for all weight transposes + q/k/v casts.
//  blocks [0, 16384): weights.  y = bx>>12 in {0..3}:
//    y<3 : [16,1024,64] -> [16,64,1024] bf16   y==3 : [1024,1024] -> transposed bf16
//  blocks [16384, 40960): q/k/v f32 -> bf16, 4 elems/thread.
__global__ void convAll_kernel(const float* __restrict__ q, const float* __restrict__ k,
                               const float* __restrict__ v,
                               const float* __restrict__ Wq, const float* __restrict__ Wk,
                               const float* __restrict__ Wv, const float* __restrict__ Wo,
                               unsigned short* __restrict__ Xq, unsigned short* __restrict__ Xk,
                               unsigned short* __restrict__ Xv,
                               unsigned short* __restrict__ WqT, unsigned short* __restrict__ WkT,
                               unsigned short* __restrict__ WvT, unsigned short* __restrict__ WoT) {
  int bx = blockIdx.x;
  if (bx < 16384) {
    int y = bx >> 12;
    int i = (bx & 4095) * 256 + threadIdx.x;
    const float* in = (y == 0) ? Wq : (y == 1) ? Wk : (y == 2) ? Wv : Wo;
    unsigned short* out = (y == 0) ? WqT : (y == 1) ? WkT : (y == 2) ? WvT : WoT;
    int S = (y < 3) ? 64 : 1024;
    int g = (y < 3) ? (i >> 16) : 0;
    int rs = (y < 3) ? (i & 65535) : i;
    int r = rs / S, s = rs % S;
    long base = (long)g * 65536;
    out[base + (long)s * 1024 + r] = f2bf(in[base + rs]);
  } else {
    int t = bx - 16384;
    int y = t >> 13;
    int i = ((t & 8191) * 256 + threadIdx.x) * 4;
    const float* in = (y == 0) ? q : (y == 1) ? k : v;
    unsigned short* out = (y == 0) ? Xq : (y == 1) ? Xk : Xv;
    f32x4 x = *(const f32x4*)(in + i);
    us4 o;
    o[0] = f2bf(x[0]); o[1] = f2bf(x[1]); o[2] = f2bf(x[2]); o[3] = f2bf(x[3]);
    *(us4*)(out + i) = o;
  }
}

// ---- shared GEMM core: 128x128 C-tile, BK=32, 4 waves 2x2, double-buffered ----
// T3-minimum schedule: prologue-stage buf0; per K-step issue next tile's
// global_load_lds into buf^1, compute from buf[cur], ONE __syncthreads per step
// (its vmcnt(0) drain lands after the MFMA work -> staging latency overlapped).
// Shared buffers are passed in (hoisted) so one kernel can instantiate the core
// twice without doubling LDS.  SWAP_=1 computes the transposed product.
#define GEMM_CORE_DB(als_, bls_, A_, B_, m0_, n0_, SWAP_)                               \
  int w = threadIdx.x >> 6, lane = threadIdx.x & 63;                                    \
  int quad = lane >> 4, mr = lane & 15;                                                 \
  int wm = w & 1, wn = w >> 1;                                                          \
  int sr = w * 16 + (lane >> 2);                                                        \
  int kofs = (((lane & 3) ^ ((sr >> 1) & 3)) << 3);                                     \
  const unsigned short* agp = (A_) + (long)((m0_) + sr) * KK + kofs;                    \
  const unsigned short* bgp = (B_) + (long)((n0_) + sr) * KK + kofs;                    \
  f32x4 acc[4][4] = {};                                                                 \
  gload16(agp, (als_) + w * 16 * 32);                                                   \
  gload16(agp + (long)64 * KK, (als_) + w * 16 * 32 + 64 * 32);                         \
  gload16(bgp, (bls_) + w * 16 * 32);                                                   \
  gload16(bgp + (long)64 * KK, (bls_) + w * 16 * 32 + 64 * 32);                         \
  __syncthreads();                                                                      \
  for (int k0 = 0; k0 < KK; k0 += 32) {                                                 \
    int cur = (k0 >> 5) & 1;                                                            \
    unsigned short* ac = (als_) + cur * (128 * 32);                                     \
    unsigned short* bc = (bls_) + cur * (128 * 32);                                     \
    if (k0 + 32 < KK) {                                                                 \
      unsigned short* an = (als_) + (cur ^ 1) * (128 * 32) + w * 16 * 32;               \
      unsigned short* bn = (bls_) + (cur ^ 1) * (128 * 32) + w * 16 * 32;               \
      gload16(agp + k0 + 32, an);                                                       \
      gload16(agp + (long)64 * KK + k0 + 32, an + 64 * 32);                             \
      gload16(bgp + k0 + 32, bn);                                                       \
      gload16(bgp + (long)64 * KK + k0 + 32, bn + 64 * 32);                             \
    }                                                                                   \
    bf16x8 af[4], bf[4];                                                                \
    _Pragma("unroll") for (int i = 0; i < 4; ++i) {                                     \
      int ar = wm * 64 + i * 16 + mr;                                                   \
      af[i] = *(const bf16x8*)(ac + ar * 32 + ((quad ^ ((ar >> 1) & 3)) << 3));         \
      int br = wn * 64 + i * 16 + mr;                                                   \
      bf[i] = *(const bf16x8*)(bc + br * 32 + ((quad ^ ((br >> 1) & 3)) << 3));         \
    }                                                                                   \
    _Pragma("unroll") for (int mi = 0; mi < 4; ++mi)                                    \
      _Pragma("unroll") for (int ni = 0; ni < 4; ++ni)                                  \
        acc[mi][ni] = (SWAP_) ? MFMA(bf[ni], af[mi], acc[mi][ni])                       \
                              : MFMA(af[mi], bf[ni], acc[mi][ni]);                      \
    __syncthreads();                                                                    \
  }

// all three input projections in ONE launch: grid dim3(512, 3) = 1536 blocks
// (vs 3 sequential 512-block launches at 2 blocks/CU -> ~4+ blocks/CU here).
// y==0: qh (pre-scaled by 0.125*log2e)  y==1: kh  y==2: vh transposed [B,H,DH,T]
__global__ __launch_bounds__(256) void proj3_kernel(
    const unsigned short* __restrict__ Xq, const unsigned short* __restrict__ Xk,
    const unsigned short* __restrict__ Xv,
    const unsigned short* __restrict__ WqT, const unsigned short* __restrict__ WkT,
    const unsigned short* __restrict__ WvT,
    unsigned short* __restrict__ qh, unsigned short* __restrict__ kh,
    unsigned short* __restrict__ vh) {
  __shared__ __align__(16) unsigned short als[2 * 128 * 32];
  __shared__ __align__(16) unsigned short bls[2 * 128 * 32];
  int y = blockIdx.y;
  int m0 = (blockIdx.x >> 3) * 128, n0 = (blockIdx.x & 7) * 128;
  if (y == 2) {
    GEMM_CORE_DB(als, bls, Xv, WvT, m0, n0, 1)
#pragma unroll
    for (int mi = 0; mi < 4; ++mi)
#pragma unroll
      for (int ni = 0; ni < 4; ++ni) {
        int token = m0 + wm * 64 + mi * 16 + mr;
        int b = token >> 11, t = token & 2047;
#pragma unroll
        for (int r = 0; r < 4; ++r) {
          int c = n0 + wn * 64 + ni * 16 + quad * 4 + r;
          int h = c >> 6, dh = c & 63;
          vh[(((long)b * HH + h) * DHH + dh) * TT + t] = f2bf(acc[mi][ni][r]);
        }
      }
  } else {
    const unsigned short* A = y ? Xk : Xq;
    const unsigned short* Bw = y ? WkT : WqT;
    unsigned short* OUT = y ? kh : qh;
    float scale = y ? 1.0f : 0.18033688011112043f;   // 0.125*log2(e)
    GEMM_CORE_DB(als, bls, A, Bw, m0, n0, 0)
#pragma unroll
    for (int mi = 0; mi < 4; ++mi)
#pragma unroll
      for (int ni = 0; ni < 4; ++ni) {
        int col = n0 + wn * 64 + ni * 16 + mr;
        int h = col >> 6, d = col & 63;
#pragma unroll
        for (int r = 0; r < 4; ++r) {
          int row = m0 + wm * 64 + mi * 16 + quad * 4 + r;
          int b = row >> 11, t = row & 2047;
          OUT[(((long)b * HH + h) * TT + t) * DHH + d] = f2bf(acc[mi][ni][r] * scale);
        }
      }
  }
}

// output projection: C[8192][1024] f32 = A.WoT^T + bo
__global__ __launch_bounds__(256) void oproj_kernel(const unsigned short* __restrict__ A,
                                                    const unsigned short* __restrict__ WoT,
                                                    const float* __restrict__ bo,
                                                    float* __restrict__ OUT) {
  __shared__ __align__(16) unsigned short als[2 * 128 * 32];
  __shared__ __align__(16) unsigned short bls[2 * 128 * 32];
  int m0 = (blockIdx.x >> 3) * 128, n0 = (blockIdx.x & 7) * 128;
  GEMM_CORE_DB(als, bls, A, WoT, m0, n0, 0)
#pragma unroll
  for (int mi = 0; mi < 4; ++mi)
#pragma unroll
    for (int ni = 0; ni < 4; ++ni) {
      int col = n0 + wn * 64 + ni * 16 + mr;
      float bias = bo[col];
#pragma unroll
      for (int r = 0; r < 4; ++r) {
        int row = m0 + wm * 64 + mi * 16 + quad * 4 + r;
        OUT[(long)row * 1024 + col] = acc[mi][ni][r] + bias;
      }
    }
}

// MFMA flash attention. QH/KH: [B,H,T,DH] ; VT: [B,H,DH,T] ; AO: [B,T,H*DH] bf16
// Q pre-scaled by 0.125*log2e -> p = exp2(S). Interior tiles skip masking.
// (round-0 version: single-buffered, measured 80.3 us; round-1's dbuf+hoist
//  +setprio bundle was neutral-to--1% -> reverted.)
__global__ __launch_bounds__(256) void attn_mfma_kernel(const unsigned short* __restrict__ QH,
                                                        const unsigned short* __restrict__ KH,
                                                        const unsigned short* __restrict__ VT,
                                                        unsigned short* __restrict__ AO) {
  __shared__ __align__(16) unsigned short kls[64 * 64];     // [s][d], chunk^=s&7
  __shared__ __align__(16) unsigned short vls[64 * 64];     // [d][s], chunk^=d&7
  __shared__ __align__(16) unsigned short pls[4 * 32 * 72]; // per wave [q][s+8]

  int w = threadIdx.x >> 6, lane = threadIdx.x & 63;
  int quad = lane >> 4, mr = lane & 15;
  int m7 = mr & 7;
  int bh = blockIdx.x & 63;            // qb-major: heavy tiles dispatch first
  int qb = 15 - (blockIdx.x >> 6);
  int q0 = qb * 128;
  int b = bh >> 4, h = bh & 15;

  const unsigned short* kbase = KH + (long)bh * TT * DHH;
  const unsigned short* vtb  = VT + (long)bh * DHH * TT;
  const unsigned short* qbp  = QH + (long)bh * TT * DHH;

  // Q fragments (MFMA B-operand for S^T): q = q0+w*32+mi*16+mr
  bf16x8 qf[2][2];
#pragma unroll
  for (int mi = 0; mi < 2; ++mi)
#pragma unroll
    for (int kd = 0; kd < 2; ++kd)
      qf[mi][kd] = *(const bf16x8*)(qbp + (long)(q0 + w * 32 + mi * 16 + mr) * DHH +
                                    kd * 32 + quad * 8);

  int srow = lane >> 3, schunk = lane & 7;
  const unsigned short* kgp = kbase + (long)(w * 16 + srow) * DHH + ((schunk ^ srow) << 3);
  const unsigned short* vgp = vtb + (long)(w * 16 + srow) * TT + ((schunk ^ srow) << 3);
  unsigned short* klu = kls + w * 16 * 64;
  unsigned short* vlu = vls + w * 16 * 64;

  f32x4 O[2][4] = {};   // [mi][nd]  row=quad*4+r (q), col=mr (d)
  float lpart[2] = {};  // per-lane softmax denominator partials (q = mi*16+mr)
  unsigned short* pw = pls + w * 32 * 72;

  for (int s0 = 0; s0 < q0 + 128; s0 += 64) {
    __syncthreads();
    gload16(kgp + (long)s0 * DHH, klu);
    gload16(kgp + (long)s0 * DHH + 8 * DHH, klu + 8 * 64);
    gload16(vgp + s0, vlu);
    gload16(vgp + s0 + 8 * TT, vlu + 8 * 64);
    __syncthreads();

#pragma unroll
    for (int mi = 0; mi < 2; ++mi) {
      int qmin = q0 + w * 32 + mi * 16;
      int qcol = qmin + mr;
#pragma unroll
      for (int sk = 0; sk < 2; ++sk) {
        int kt0 = s0 + sk * 32;
        if (kt0 > qmin + 15) continue;         // wave-uniform skip
        bool full = (kt0 + 31 <= qmin);        // wave-uniform: no mask needed
#pragma unroll
        for (int nh = 0; nh < 2; ++nh) {
          int ns = sk * 2 + nh;
          int krow = ns * 16 + mr;
          int p0 = quad ^ m7;
          bf16x8 kf0 = *(const bf16x8*)&kls[krow * 64 + p0 * 8];
          bf16x8 kf1 = *(const bf16x8*)&kls[krow * 64 + (p0 ^ 4) * 8];
          f32x4 acc = {};
          acc = MFMA(kf0, qf[mi][0], acc);
          acc = MFMA(kf1, qf[mi][1], acc);
          float pe0, pe1, pe2, pe3;
          if (full) {
            pe0 = __builtin_amdgcn_exp2f(acc[0]);
            pe1 = __builtin_amdgcn_exp2f(acc[1]);
            pe2 = __builtin_amdgcn_exp2f(acc[2]);
            pe3 = __builtin_amdgcn_exp2f(acc[3]);
          } else {
            int sbase = s0 + ns * 16 + quad * 4;
            pe0 = (sbase + 0 <= qcol) ? __builtin_amdgcn_exp2f(acc[0]) : 0.f;
            pe1 = (sbase + 1 <= qcol) ? __builtin_amdgcn_exp2f(acc[1]) : 0.f;
            pe2 = (sbase + 2 <= qcol) ? __builtin_amdgcn_exp2f(acc[2]) : 0.f;
            pe3 = (sbase + 3 <= qcol) ? __builtin_amdgcn_exp2f(acc[3]) : 0.f;
          }
          lpart[mi] += (pe0 + pe1) + (pe2 + pe3);
          u32x2 pk;
          pk[0] = pack2bf(pe0, pe1);
          pk[1] = pack2bf(pe2, pe3);
          *(u32x2*)&pw[(mi * 16 + mr) * 72 + ns * 16 + quad * 4] = pk;
        }
        // --- O += P V  (A=P from pls, B=V^T from vls; same-wave LDS, no barrier) ---
        bf16x8 pf = *(const bf16x8*)&pw[(mi * 16 + mr) * 72 + sk * 32 + quad * 8];
        int pv = (sk * 4 + quad) ^ m7;
#pragma unroll
        for (int nd = 0; nd < 4; ++nd) {
          bf16x8 vf = *(const bf16x8*)&vls[(nd * 16 + mr) * 64 + pv * 8];
          O[mi][nd] = MFMA(pf, vf, O[mi][nd]);
        }
      }
    }
  }

  // reduce denominators across quads; lane holds 1/l for q = mi*16+mr
  float rl[2];
#pragma unroll
  for (int mi = 0; mi < 2; ++mi) {
    float s = lpart[mi];
    s += __shfl_xor(s, 16);
    s += __shfl_xor(s, 32);
    rl[mi] = 1.0f / s;
  }
#pragma unroll
  for (int mi = 0; mi < 2; ++mi) {
#pragma unroll
    for (int r = 0; r < 4; ++r) {
      float rlr = __shfl(rl[mi], (lane & 48) | (quad * 4 + r));
      int t = q0 + w * 32 + mi * 16 + quad * 4 + r;
      unsigned short* orow = AO + ((long)(b * TT + t)) * (HH * DHH) + h * DHH + mr;
#pragma unroll
      for (int nd = 0; nd < 4; ++nd)
        orow[nd * 16] = f2bf(O[mi][nd][r] * rlr);
    }
  }
}

extern "C" void kernel_launch(void* const* d_in, const int* in_sizes, int n_in,
                              void* d_out, int out_size, void* d_ws, size_t ws_size,
                              hipStream_t stream) {
  const float* k  = (const float*)d_in[0];
  const float* q  = (const float*)d_in[1];
  const float* v  = (const float*)d_in[2];
  const float* Wk = (const float*)d_in[3];
  const float* Wq = (const float*)d_in[4];
  const float* Wv = (const float*)d_in[5];
  const float* Wo = (const float*)d_in[6];
  const float* bo = (const float*)d_in[7];
  float* out = (float*)d_out;

  const size_t PROJ = (size_t)BB * HH * TT * DHH;  // 8.39M elems
  const size_t WSZ  = (size_t)HH * DHH * CC;       // 1.05M elems
  unsigned short* qh  = (unsigned short*)d_ws;
  unsigned short* kh  = qh + PROJ;
  unsigned short* vh  = kh + PROJ;                 // [B,H,DH,T] (transposed)
  unsigned short* WqT = vh + PROJ;
  unsigned short* WkT = WqT + WSZ;
  unsigned short* WvT = WkT + WSZ;
  unsigned short* WoT = WvT + WSZ;
  unsigned short* AO  = WoT + WSZ;                 // B*T*1024 bf16
  unsigned short* Xq  = AO;                        // alias: dead before attn writes AO
  unsigned short* Xk  = (unsigned short*)out;      // d_out doubles as bf16 scratch
  unsigned short* Xv  = Xk + PROJ;                 // (fully overwritten by oproj later)

  convAll_kernel<<<40960, 256, 0, stream>>>(q, k, v, Wq, Wk, Wv, Wo,
                                            Xq, Xk, Xv, WqT, WkT, WvT, WoT);
  proj3_kernel<<<dim3(512, 3), 256, 0, stream>>>(Xq, Xk, Xv, WqT, WkT, WvT, qh, kh, vh);
  attn_mfma_kernel<<<BB * HH * (TT / 128), 256, 0, stream>>>(qh, kh, vh, AO);
  oproj_kernel<<<512, 256, 0, stream>>>(AO, WoT, bo, out);
}

// Round 3
// 310.935 us; speedup vs baseline: 1.1421x; 1.0882x over previous
//
#include <hip/hip_runtime.h>

#define BB 4
#define TT 2048
#define CC 1024
#define HH 16
#define DHH 64
#define KK 1024   // GEMM K dim (= CC)

typedef __attribute__((ext_vector_type(4))) float f32x4;
typedef __attribute__((ext_vector_type(8))) short bf16x8;
typedef __attribute__((ext_vector_type(4))) unsigned short us4;
typedef __attribute__((ext_vector_type(2))) unsigned int u32x2;

#define MFMA(a, b, c) __builtin_amdgcn_mfma_f32_16x16x32_bf16((a), (b), (c), 0, 0, 0)

typedef const __attribute__((address_space(1))) unsigned int* gas_t;
typedef __attribute__((address_space(3))) unsigned int* las_t;
__device__ __forceinline__ void gload16(const unsigned short* g, unsigned short* l) {
  // async global->LDS, 16B/lane; LDS dest = wave-uniform base + lane*16
  __builtin_amdgcn_global_load_lds((gas_t)g, (las_t)l, 16, 0, 0);
}

__device__ __forceinline__ unsigned short f2bf(float x) {
  unsigned u = __builtin_bit_cast(unsigned, x);
  u += 0x7FFF + ((u >> 16) & 1);   // RNE; finite inputs
  return (unsigned short)(u >> 16);
}

#if __has_builtin(__builtin_amdgcn_cvt_pk_bf16_f32)
__device__ __forceinline__ unsigned pack2bf(float a, float b) {
  auto v = __builtin_amdgcn_cvt_pk_bf16_f32(a, b);   // v_cvt_pk_bf16_f32 (gfx950)
  return __builtin_bit_cast(unsigned, v);
}
#else
__device__ __forceinline__ unsigned pack2bf(float a, float b) {
  return (unsigned)f2bf(a) | ((unsigned)f2bf(b) << 16);
}
#endif

// fused conversion pass: one launch for all weight transposes + q/k/v casts.
//  blocks [0, 16384): weights.  y = bx>>12 in {0..3}:
//    y<3 : [16,1024,64] -> [16,64,1024] bf16   y==3 : [1024,1024] -> transposed bf16
//  blocks [16384, 40960): q/k/v f32 -> bf16, 4 elems/thread.
__global__ void convAll_kernel(const float* __restrict__ q, const float* __restrict__ k,
                               const float* __restrict__ v,
                               const float* __restrict__ Wq, const float* __restrict__ Wk,
                               const float* __restrict__ Wv, const float* __restrict__ Wo,
                               unsigned short* __restrict__ Xq, unsigned short* __restrict__ Xk,
                               unsigned short* __restrict__ Xv,
                               unsigned short* __restrict__ WqT, unsigned short* __restrict__ WkT,
                               unsigned short* __restrict__ WvT, unsigned short* __restrict__ WoT) {
  int bx = blockIdx.x;
  if (bx < 16384) {
    int y = bx >> 12;
    int i = (bx & 4095) * 256 + threadIdx.x;
    const float* in = (y == 0) ? Wq : (y == 1) ? Wk : (y == 2) ? Wv : Wo;
    unsigned short* out = (y == 0) ? WqT : (y == 1) ? WkT : (y == 2) ? WvT : WoT;
    int S = (y < 3) ? 64 : 1024;
    int g = (y < 3) ? (i >> 16) : 0;
    int rs = (y < 3) ? (i & 65535) : i;
    int r = rs / S, s = rs % S;
    long base = (long)g * 65536;
    out[base + (long)s * 1024 + r] = f2bf(in[base + rs]);
  } else {
    int t = bx - 16384;
    int y = t >> 13;
    int i = ((t & 8191) * 256 + threadIdx.x) * 4;
    const float* in = (y == 0) ? q : (y == 1) ? k : v;
    unsigned short* out = (y == 0) ? Xq : (y == 1) ? Xk : Xv;
    f32x4 x = *(const f32x4*)(in + i);
    us4 o;
    o[0] = f2bf(x[0]); o[1] = f2bf(x[1]); o[2] = f2bf(x[2]); o[3] = f2bf(x[3]);
    *(us4*)(out + i) = o;
  }
}

// ---- shared GEMM core: 128x128 C-tile, BK=32, 4 waves 2x2, double-buffered ----
// T3-minimum schedule: prologue-stage buf0; per K-step issue next tile's
// global_load_lds into buf^1, compute from buf[cur], ONE __syncthreads per step
// (its vmcnt(0) drain lands after the MFMA work -> staging latency overlapped).
#define GEMM_CORE_DB(als_, bls_, A_, B_, m0_, n0_, SWAP_)                               \
  int w = threadIdx.x >> 6, lane = threadIdx.x & 63;                                    \
  int quad = lane >> 4, mr = lane & 15;                                                 \
  int wm = w & 1, wn = w >> 1;                                                          \
  int sr = w * 16 + (lane >> 2);                                                        \
  int kofs = (((lane & 3) ^ ((sr >> 1) & 3)) << 3);                                     \
  const unsigned short* agp = (A_) + (long)((m0_) + sr) * KK + kofs;                    \
  const unsigned short* bgp = (B_) + (long)((n0_) + sr) * KK + kofs;                    \
  f32x4 acc[4][4] = {};                                                                 \
  gload16(agp, (als_) + w * 16 * 32);                                                   \
  gload16(agp + (long)64 * KK, (als_) + w * 16 * 32 + 64 * 32);                         \
  gload16(bgp, (bls_) + w * 16 * 32);                                                   \
  gload16(bgp + (long)64 * KK, (bls_) + w * 16 * 32 + 64 * 32);                         \
  __syncthreads();                                                                      \
  for (int k0 = 0; k0 < KK; k0 += 32) {                                                 \
    int cur = (k0 >> 5) & 1;                                                            \
    unsigned short* ac = (als_) + cur * (128 * 32);                                     \
    unsigned short* bc = (bls_) + cur * (128 * 32);                                     \
    if (k0 + 32 < KK) {                                                                 \
      unsigned short* an = (als_) + (cur ^ 1) * (128 * 32) + w * 16 * 32;               \
      unsigned short* bn = (bls_) + (cur ^ 1) * (128 * 32) + w * 16 * 32;               \
      gload16(agp + k0 + 32, an);                                                       \
      gload16(agp + (long)64 * KK + k0 + 32, an + 64 * 32);                             \
      gload16(bgp + k0 + 32, bn);                                                       \
      gload16(bgp + (long)64 * KK + k0 + 32, bn + 64 * 32);                             \
    }                                                                                   \
    bf16x8 af[4], bf[4];                                                                \
    _Pragma("unroll") for (int i = 0; i < 4; ++i) {                                     \
      int ar = wm * 64 + i * 16 + mr;                                                   \
      af[i] = *(const bf16x8*)(ac + ar * 32 + ((quad ^ ((ar >> 1) & 3)) << 3));         \
      int br = wn * 64 + i * 16 + mr;                                                   \
      bf[i] = *(const bf16x8*)(bc + br * 32 + ((quad ^ ((br >> 1) & 3)) << 3));         \
    }                                                                                   \
    _Pragma("unroll") for (int mi = 0; mi < 4; ++mi)                                    \
      _Pragma("unroll") for (int ni = 0; ni < 4; ++ni)                                  \
        acc[mi][ni] = (SWAP_) ? MFMA(bf[ni], af[mi], acc[mi][ni])                       \
                              : MFMA(af[mi], bf[ni], acc[mi][ni]);                      \
    __syncthreads();                                                                    \
  }

// all three input projections in ONE flat launch of 1536 blocks.
// XCD-chunked bijective swizzle (T1): consecutive dispatched blocks round-robin
// across the 8 XCDs, so lin = (bid%8)*192 + bid/8 gives each XCD a CONTIGUOUS
// run of (y, m-panel) work -> A-panels and the 2 MB W panel stay in that XCD's
// 4 MB L2 instead of being re-fetched 8x from HBM (r2 FETCH: 201 MB vs 56 ideal).
// y==0: qh (pre-scaled by 0.125*log2e)  y==1: kh  y==2: vh transposed [B,H,DH,T]
__global__ __launch_bounds__(256) void proj3_kernel(
    const unsigned short* __restrict__ Xq, const unsigned short* __restrict__ Xk,
    const unsigned short* __restrict__ Xv,
    const unsigned short* __restrict__ WqT, const unsigned short* __restrict__ WkT,
    const unsigned short* __restrict__ WvT,
    unsigned short* __restrict__ qh, unsigned short* __restrict__ kh,
    unsigned short* __restrict__ vh) {
  __shared__ __align__(16) unsigned short als[2 * 128 * 32];
  __shared__ __align__(16) unsigned short bls[2 * 128 * 32];
  int bid = blockIdx.x;
  int lin = (bid & 7) * 192 + (bid >> 3);   // 1536 % 8 == 0: bijective
  int y = lin >> 9;
  int tile = lin & 511;
  int m0 = (tile >> 3) * 128, n0 = (tile & 7) * 128;
  if (y == 2) {
    GEMM_CORE_DB(als, bls, Xv, WvT, m0, n0, 1)
#pragma unroll
    for (int mi = 0; mi < 4; ++mi)
#pragma unroll
      for (int ni = 0; ni < 4; ++ni) {
        int token = m0 + wm * 64 + mi * 16 + mr;
        int b = token >> 11, t = token & 2047;
#pragma unroll
        for (int r = 0; r < 4; ++r) {
          int c = n0 + wn * 64 + ni * 16 + quad * 4 + r;
          int h = c >> 6, dh = c & 63;
          vh[(((long)b * HH + h) * DHH + dh) * TT + t] = f2bf(acc[mi][ni][r]);
        }
      }
  } else {
    const unsigned short* A = y ? Xk : Xq;
    const unsigned short* Bw = y ? WkT : WqT;
    unsigned short* OUT = y ? kh : qh;
    float scale = y ? 1.0f : 0.18033688011112043f;   // 0.125*log2(e)
    GEMM_CORE_DB(als, bls, A, Bw, m0, n0, 0)
#pragma unroll
    for (int mi = 0; mi < 4; ++mi)
#pragma unroll
      for (int ni = 0; ni < 4; ++ni) {
        int col = n0 + wn * 64 + ni * 16 + mr;
        int h = col >> 6, d = col & 63;
#pragma unroll
        for (int r = 0; r < 4; ++r) {
          int row = m0 + wm * 64 + mi * 16 + quad * 4 + r;
          int b = row >> 11, t = row & 2047;
          OUT[(((long)b * HH + h) * TT + t) * DHH + d] = f2bf(acc[mi][ni][r] * scale);
        }
      }
  }
}

// output projection: C[8192][1024] f32 = A.WoT^T + bo  (same XCD swizzle)
__global__ __launch_bounds__(256) void oproj_kernel(const unsigned short* __restrict__ A,
                                                    const unsigned short* __restrict__ WoT,
                                                    const float* __restrict__ bo,
                                                    float* __restrict__ OUT) {
  __shared__ __align__(16) unsigned short als[2 * 128 * 32];
  __shared__ __align__(16) unsigned short bls[2 * 128 * 32];
  int bid = blockIdx.x;
  int lin = (bid & 7) * 64 + (bid >> 3);    // 512 % 8 == 0: bijective
  int m0 = (lin >> 3) * 128, n0 = (lin & 7) * 128;
  GEMM_CORE_DB(als, bls, A, WoT, m0, n0, 0)
#pragma unroll
  for (int mi = 0; mi < 4; ++mi)
#pragma unroll
    for (int ni = 0; ni < 4; ++ni) {
      int col = n0 + wn * 64 + ni * 16 + mr;
      float bias = bo[col];
#pragma unroll
      for (int r = 0; r < 4; ++r) {
        int row = m0 + wm * 64 + mi * 16 + quad * 4 + r;
        OUT[(long)row * 1024 + col] = acc[mi][ni][r] + bias;
      }
    }
}

// MFMA flash attention. QH/KH: [B,H,T,DH] ; VT: [B,H,DH,T] ; AO: [B,T,H*DH] bf16
// Q pre-scaled by 0.125*log2e -> p = exp2(S). Interior tiles skip masking.
// r3: QBLK 128 -> 64 (grid 2048, wave owns 16 q-rows). r2 showed occupancy 26%
// (grid = exactly 4 blk/CU, 16:1 work imbalance); finer blocks double the grid
// and halve the tail quantum. pls shrunk to one-sk depth -> LDS 34.8 -> 21.5 KB
// (7 blocks/CU cap). KVBLK=64 staging structure unchanged.
__global__ __launch_bounds__(256) void attn_mfma_kernel(const unsigned short* __restrict__ QH,
                                                        const unsigned short* __restrict__ KH,
                                                        const unsigned short* __restrict__ VT,
                                                        unsigned short* __restrict__ AO) {
  __shared__ __align__(16) unsigned short kls[64 * 64];     // [s][d], chunk^=s&7
  __shared__ __align__(16) unsigned short vls[64 * 64];     // [d][s], chunk^=d&7
  __shared__ __align__(16) unsigned short pls[4 * 16 * 40]; // per wave [q][32k + pad]

  int w = threadIdx.x >> 6, lane = threadIdx.x & 63;
  int quad = lane >> 4, mr = lane & 15;
  int m7 = mr & 7;
  int bh = blockIdx.x & 63;            // qb-major: heavy tiles dispatch first;
  int qb = 31 - (blockIdx.x >> 6);     // fixed bh stays on one XCD (ids differ by 64)
  int q0 = qb * 64;
  int b = bh >> 4, h = bh & 15;

  const unsigned short* kbase = KH + (long)bh * TT * DHH;
  const unsigned short* vtb  = VT + (long)bh * DHH * TT;
  const unsigned short* qbp  = QH + (long)bh * TT * DHH;

  // Q fragments (MFMA B-operand for S^T): q = q0 + w*16 + mr
  bf16x8 qf[2];
#pragma unroll
  for (int kd = 0; kd < 2; ++kd)
    qf[kd] = *(const bf16x8*)(qbp + (long)(q0 + w * 16 + mr) * DHH + kd * 32 + quad * 8);

  int srow = lane >> 3, schunk = lane & 7;
  const unsigned short* kgp = kbase + (long)(w * 16 + srow) * DHH + ((schunk ^ srow) << 3);
  const unsigned short* vgp = vtb + (long)(w * 16 + srow) * TT + ((schunk ^ srow) << 3);
  unsigned short* klu = kls + w * 16 * 64;
  unsigned short* vlu = vls + w * 16 * 64;

  f32x4 O[4] = {};     // [nd]  row=quad*4+r (q), col=mr (d)
  float lpart = 0.f;   // per-lane softmax denominator partial (q = qmin+mr)
  unsigned short* pw = pls + w * 16 * 40;
  int qmin = q0 + w * 16;
  int qcol = qmin + mr;

  for (int s0 = 0; s0 < q0 + 64; s0 += 64) {
    __syncthreads();
    gload16(kgp + (long)s0 * DHH, klu);
    gload16(kgp + (long)s0 * DHH + 8 * DHH, klu + 8 * 64);
    gload16(vgp + s0, vlu);
    gload16(vgp + s0 + 8 * TT, vlu + 8 * 64);
    __syncthreads();

#pragma unroll
    for (int sk = 0; sk < 2; ++sk) {
      int kt0 = s0 + sk * 32;
      if (kt0 > qmin + 15) continue;         // wave-uniform skip
      bool full = (kt0 + 31 <= qmin);        // wave-uniform: no mask needed
#pragma unroll
      for (int nh = 0; nh < 2; ++nh) {
        int ns = sk * 2 + nh;
        int krow = ns * 16 + mr;
        int p0 = quad ^ m7;
        bf16x8 kf0 = *(const bf16x8*)&kls[krow * 64 + p0 * 8];
        bf16x8 kf1 = *(const bf16x8*)&kls[krow * 64 + (p0 ^ 4) * 8];
        f32x4 acc = {};
        acc = MFMA(kf0, qf[0], acc);
        acc = MFMA(kf1, qf[1], acc);
        float pe0, pe1, pe2, pe3;
        if (full) {
          pe0 = __builtin_amdgcn_exp2f(acc[0]);
          pe1 = __builtin_amdgcn_exp2f(acc[1]);
          pe2 = __builtin_amdgcn_exp2f(acc[2]);
          pe3 = __builtin_amdgcn_exp2f(acc[3]);
        } else {
          int sbase = s0 + ns * 16 + quad * 4;
          pe0 = (sbase + 0 <= qcol) ? __builtin_amdgcn_exp2f(acc[0]) : 0.f;
          pe1 = (sbase + 1 <= qcol) ? __builtin_amdgcn_exp2f(acc[1]) : 0.f;
          pe2 = (sbase + 2 <= qcol) ? __builtin_amdgcn_exp2f(acc[2]) : 0.f;
          pe3 = (sbase + 3 <= qcol) ? __builtin_amdgcn_exp2f(acc[3]) : 0.f;
        }
        lpart += (pe0 + pe1) + (pe2 + pe3);
        u32x2 pk;
        pk[0] = pack2bf(pe0, pe1);
        pk[1] = pack2bf(pe2, pe3);
        *(u32x2*)&pw[mr * 40 + nh * 16 + quad * 4] = pk;
      }
      // --- O += P V  (A=P from pls, B=V^T from vls; same-wave LDS, no barrier) ---
      bf16x8 pf = *(const bf16x8*)&pw[mr * 40 + quad * 8];
      int pv = (sk * 4 + quad) ^ m7;
#pragma unroll
      for (int nd = 0; nd < 4; ++nd) {
        bf16x8 vf = *(const bf16x8*)&vls[(nd * 16 + mr) * 64 + pv * 8];
        O[nd] = MFMA(pf, vf, O[nd]);
      }
    }
  }

  // reduce denominators across quads; lane holds 1/l for q = qmin+mr
  float s = lpart;
  s += __shfl_xor(s, 16);
  s += __shfl_xor(s, 32);
  float rl = 1.0f / s;
#pragma unroll
  for (int r = 0; r < 4; ++r) {
    float rlr = __shfl(rl, (lane & 48) | (quad * 4 + r));
    int t = q0 + w * 16 + quad * 4 + r;
    unsigned short* orow = AO + ((long)(b * TT + t)) * (HH * DHH) + h * DHH + mr;
#pragma unroll
    for (int nd = 0; nd < 4; ++nd)
      orow[nd * 16] = f2bf(O[nd][r] * rlr);
  }
}

extern "C" void kernel_launch(void* const* d_in, const int* in_sizes, int n_in,
                              void* d_out, int out_size, void* d_ws, size_t ws_size,
                              hipStream_t stream) {
  const float* k  = (const float*)d_in[0];
  const float* q  = (const float*)d_in[1];
  const float* v  = (const float*)d_in[2];
  const float* Wk = (const float*)d_in[3];
  const float* Wq = (const float*)d_in[4];
  const float* Wv = (const float*)d_in[5];
  const float* Wo = (const float*)d_in[6];
  const float* bo = (const float*)d_in[7];
  float* out = (float*)d_out;

  const size_t PROJ = (size_t)BB * HH * TT * DHH;  // 8.39M elems
  const size_t WSZ  = (size_t)HH * DHH * CC;       // 1.05M elems
  unsigned short* qh  = (unsigned short*)d_ws;
  unsigned short* kh  = qh + PROJ;
  unsigned short* vh  = kh + PROJ;                 // [B,H,DH,T] (transposed)
  unsigned short* WqT = vh + PROJ;
  unsigned short* WkT = WqT + WSZ;
  unsigned short* WvT = WkT + WSZ;
  unsigned short* WoT = WvT + WSZ;
  unsigned short* AO  = WoT + WSZ;                 // B*T*1024 bf16
  unsigned short* Xq  = AO;                        // alias: dead before attn writes AO
  unsigned short* Xk  = (unsigned short*)out;      // d_out doubles as bf16 scratch
  unsigned short* Xv  = Xk + PROJ;                 // (fully overwritten by oproj later)

  convAll_kernel<<<40960, 256, 0, stream>>>(q, k, v, Wq, Wk, Wv, Wo,
                                            Xq, Xk, Xv, WqT, WkT, WvT, WoT);
  proj3_kernel<<<1536, 256, 0, stream>>>(Xq, Xk, Xv, WqT, WkT, WvT, qh, kh, vh);
  attn_mfma_kernel<<<BB * HH * (TT / 64), 256, 0, stream>>>(qh, kh, vh, AO);
  oproj_kernel<<<512, 256, 0, stream>>>(AO, WoT, bo, out);
}

// Round 4
// 293.052 us; speedup vs baseline: 1.2118x; 1.0610x over previous
//
#include <hip/hip_runtime.h>

#define BB 4
#define TT 2048
#define CC 1024
#define HH 16
#define DHH 64
#define KK 1024   // GEMM K dim (= CC)

typedef __attribute__((ext_vector_type(4))) float f32x4;
typedef __attribute__((ext_vector_type(8))) short bf16x8;
typedef __attribute__((ext_vector_type(4))) unsigned short us4;
typedef __attribute__((ext_vector_type(2))) unsigned int u32x2;

#define MFMA(a, b, c) __builtin_amdgcn_mfma_f32_16x16x32_bf16((a), (b), (c), 0, 0, 0)

typedef const __attribute__((address_space(1))) unsigned int* gas_t;
typedef __attribute__((address_space(3))) unsigned int* las_t;
__device__ __forceinline__ void gload16(const unsigned short* g, unsigned short* l) {
  // async global->LDS, 16B/lane; LDS dest = wave-uniform base + lane*16
  __builtin_amdgcn_global_load_lds((gas_t)g, (las_t)l, 16, 0, 0);
}

__device__ __forceinline__ unsigned short f2bf(float x) {
  unsigned u = __builtin_bit_cast(unsigned, x);
  u += 0x7FFF + ((u >> 16) & 1);   // RNE; finite inputs
  return (unsigned short)(u >> 16);
}

#if __has_builtin(__builtin_amdgcn_cvt_pk_bf16_f32)
__device__ __forceinline__ unsigned pack2bf(float a, float b) {
  auto v = __builtin_amdgcn_cvt_pk_bf16_f32(a, b);   // v_cvt_pk_bf16_f32 (gfx950)
  return __builtin_bit_cast(unsigned, v);
}
#else
__device__ __forceinline__ unsigned pack2bf(float a, float b) {
  return (unsigned)f2bf(a) | ((unsigned)f2bf(b) << 16);
}
#endif

// fused conversion pass.
//  blocks [0, 1024): weight transpose via 64x64 LDS tiles (coalesced read AND
//    write; the old scalar path wrote bf16 at stride 1024/2048B -> ~32x write
//    amplification on 6.6 MB of weights).
//    [0,768): Wq/Wk/Wv  [16,1024,64] -> [16,64,1024]   (256 tiles each)
//    [768,1024): Wo     [1024,1024]  -> transposed     (256 tiles)
//  blocks [1024, 25600): q/k/v f32 -> bf16, 4 elems/thread, coalesced.
__global__ void convAll_kernel(const float* __restrict__ q, const float* __restrict__ k,
                               const float* __restrict__ v,
                               const float* __restrict__ Wq, const float* __restrict__ Wk,
                               const float* __restrict__ Wv, const float* __restrict__ Wo,
                               unsigned short* __restrict__ Xq, unsigned short* __restrict__ Xk,
                               unsigned short* __restrict__ Xv,
                               unsigned short* __restrict__ WqT, unsigned short* __restrict__ WkT,
                               unsigned short* __restrict__ WvT, unsigned short* __restrict__ WoT) {
  int bx = blockIdx.x;
  if (bx < 1024) {
    __shared__ float ls[64][65];    // +1 pad: conflict-free transposed reads
    const float* in;
    unsigned short* out;
    long base;
    int r0, s0, S;
    if (bx < 768) {
      int y = bx >> 8;
      int idx = bx & 255;
      in = (y == 0) ? Wq : (y == 1) ? Wk : Wv;
      out = (y == 0) ? WqT : (y == 1) ? WkT : WvT;
      int g = idx >> 4;             // head
      r0 = (idx & 15) * 64;
      s0 = 0;
      S = 64;
      base = (long)g * 65536;
    } else {
      int idx = bx - 768;
      in = Wo;
      out = WoT;
      r0 = (idx >> 4) * 64;
      s0 = (idx & 15) * 64;
      S = 1024;
      base = 0;
    }
    int tr = threadIdx.x >> 6;      // 0..3
    int tc = threadIdx.x & 63;
#pragma unroll
    for (int it = 0; it < 16; ++it) {
      int rr = it * 4 + tr;
      ls[rr][tc] = in[base + (long)(r0 + rr) * S + s0 + tc];
    }
    __syncthreads();
#pragma unroll
    for (int it = 0; it < 16; ++it) {
      int ss = it * 4 + tr;
      out[base + (long)(s0 + ss) * 1024 + r0 + tc] = f2bf(ls[tc][ss]);
    }
  } else {
    int t = bx - 1024;
    int y = t >> 13;
    int i = ((t & 8191) * 256 + threadIdx.x) * 4;
    const float* in = (y == 0) ? q : (y == 1) ? k : v;
    unsigned short* out = (y == 0) ? Xq : (y == 1) ? Xk : Xv;
    f32x4 x = *(const f32x4*)(in + i);
    us4 o;
    o[0] = f2bf(x[0]); o[1] = f2bf(x[1]); o[2] = f2bf(x[2]); o[3] = f2bf(x[3]);
    *(us4*)(out + i) = o;
  }
}

// ---- shared GEMM core: 128x128 C-tile, BK=32, 4 waves 2x2, double-buffered ----
#define GEMM_CORE_DB(als_, bls_, A_, B_, m0_, n0_, SWAP_)                               \
  int w = threadIdx.x >> 6, lane = threadIdx.x & 63;                                    \
  int quad = lane >> 4, mr = lane & 15;                                                 \
  int wm = w & 1, wn = w >> 1;                                                          \
  int sr = w * 16 + (lane >> 2);                                                        \
  int kofs = (((lane & 3) ^ ((sr >> 1) & 3)) << 3);                                     \
  const unsigned short* agp = (A_) + (long)((m0_) + sr) * KK + kofs;                    \
  const unsigned short* bgp = (B_) + (long)((n0_) + sr) * KK + kofs;                    \
  f32x4 acc[4][4] = {};                                                                 \
  gload16(agp, (als_) + w * 16 * 32);                                                   \
  gload16(agp + (long)64 * KK, (als_) + w * 16 * 32 + 64 * 32);                         \
  gload16(bgp, (bls_) + w * 16 * 32);                                                   \
  gload16(bgp + (long)64 * KK, (bls_) + w * 16 * 32 + 64 * 32);                         \
  __syncthreads();                                                                      \
  for (int k0 = 0; k0 < KK; k0 += 32) {                                                 \
    int cur = (k0 >> 5) & 1;                                                            \
    unsigned short* ac = (als_) + cur * (128 * 32);                                     \
    unsigned short* bc = (bls_) + cur * (128 * 32);                                     \
    if (k0 + 32 < KK) {                                                                 \
      unsigned short* an = (als_) + (cur ^ 1) * (128 * 32) + w * 16 * 32;               \
      unsigned short* bn = (bls_) + (cur ^ 1) * (128 * 32) + w * 16 * 32;               \
      gload16(agp + k0 + 32, an);                                                       \
      gload16(agp + (long)64 * KK + k0 + 32, an + 64 * 32);                             \
      gload16(bgp + k0 + 32, bn);                                                       \
      gload16(bgp + (long)64 * KK + k0 + 32, bn + 64 * 32);                             \
    }                                                                                   \
    bf16x8 af[4], bf[4];                                                                \
    _Pragma("unroll") for (int i = 0; i < 4; ++i) {                                     \
      int ar = wm * 64 + i * 16 + mr;                                                   \
      af[i] = *(const bf16x8*)(ac + ar * 32 + ((quad ^ ((ar >> 1) & 3)) << 3));         \
      int br = wn * 64 + i * 16 + mr;                                                   \
      bf[i] = *(const bf16x8*)(bc + br * 32 + ((quad ^ ((br >> 1) & 3)) << 3));         \
    }                                                                                   \
    _Pragma("unroll") for (int mi = 0; mi < 4; ++mi)                                    \
      _Pragma("unroll") for (int ni = 0; ni < 4; ++ni)                                  \
        acc[mi][ni] = (SWAP_) ? MFMA(bf[ni], af[mi], acc[mi][ni])                       \
                              : MFMA(af[mi], bf[ni], acc[mi][ni]);                      \
    __syncthreads();                                                                    \
  }

// all three input projections in ONE flat launch of 1536 blocks.
// XCD-chunked bijective swizzle (T1): lin = (bid%8)*192 + bid/8.
// y==0: qh (pre-scaled by 0.125*log2e)  y==1: kh  y==2: vh transposed [B,H,DH,T]
__global__ __launch_bounds__(256) void proj3_kernel(
    const unsigned short* __restrict__ Xq, const unsigned short* __restrict__ Xk,
    const unsigned short* __restrict__ Xv,
    const unsigned short* __restrict__ WqT, const unsigned short* __restrict__ WkT,
    const unsigned short* __restrict__ WvT,
    unsigned short* __restrict__ qh, unsigned short* __restrict__ kh,
    unsigned short* __restrict__ vh) {
  __shared__ __align__(16) unsigned short als[2 * 128 * 32];
  __shared__ __align__(16) unsigned short bls[2 * 128 * 32];
  int bid = blockIdx.x;
  int lin = (bid & 7) * 192 + (bid >> 3);   // 1536 % 8 == 0: bijective
  int y = lin >> 9;
  int tile = lin & 511;
  int m0 = (tile >> 3) * 128, n0 = (tile & 7) * 128;
  if (y == 2) {
    GEMM_CORE_DB(als, bls, Xv, WvT, m0, n0, 1)
#pragma unroll
    for (int mi = 0; mi < 4; ++mi)
#pragma unroll
      for (int ni = 0; ni < 4; ++ni) {
        int token = m0 + wm * 64 + mi * 16 + mr;
        int b = token >> 11, t = token & 2047;
#pragma unroll
        for (int r = 0; r < 4; ++r) {
          int c = n0 + wn * 64 + ni * 16 + quad * 4 + r;
          int h = c >> 6, dh = c & 63;
          vh[(((long)b * HH + h) * DHH + dh) * TT + t] = f2bf(acc[mi][ni][r]);
        }
      }
  } else {
    const unsigned short* A = y ? Xk : Xq;
    const unsigned short* Bw = y ? WkT : WqT;
    unsigned short* OUT = y ? kh : qh;
    float scale = y ? 1.0f : 0.18033688011112043f;   // 0.125*log2(e)
    GEMM_CORE_DB(als, bls, A, Bw, m0, n0, 0)
#pragma unroll
    for (int mi = 0; mi < 4; ++mi)
#pragma unroll
      for (int ni = 0; ni < 4; ++ni) {
        int col = n0 + wn * 64 + ni * 16 + mr;
        int h = col >> 6, d = col & 63;
#pragma unroll
        for (int r = 0; r < 4; ++r) {
          int row = m0 + wm * 64 + mi * 16 + quad * 4 + r;
          int b = row >> 11, t = row & 2047;
          OUT[(((long)b * HH + h) * TT + t) * DHH + d] = f2bf(acc[mi][ni][r] * scale);
        }
      }
  }
}

// output projection: C[8192][1024] f32 = A.WoT^T + bo  (same XCD swizzle)
__global__ __launch_bounds__(256) void oproj_kernel(const unsigned short* __restrict__ A,
                                                    const unsigned short* __restrict__ WoT,
                                                    const float* __restrict__ bo,
                                                    float* __restrict__ OUT) {
  __shared__ __align__(16) unsigned short als[2 * 128 * 32];
  __shared__ __align__(16) unsigned short bls[2 * 128 * 32];
  int bid = blockIdx.x;
  int lin = (bid & 7) * 64 + (bid >> 3);    // 512 % 8 == 0: bijective
  int m0 = (lin >> 3) * 128, n0 = (lin & 7) * 128;
  GEMM_CORE_DB(als, bls, A, WoT, m0, n0, 0)
#pragma unroll
  for (int mi = 0; mi < 4; ++mi)
#pragma unroll
    for (int ni = 0; ni < 4; ++ni) {
      int col = n0 + wn * 64 + ni * 16 + mr;
      float bias = bo[col];
#pragma unroll
      for (int r = 0; r < 4; ++r) {
        int row = m0 + wm * 64 + mi * 16 + quad * 4 + r;
        OUT[(long)row * 1024 + col] = acc[mi][ni][r] + bias;
      }
    }
}

// MFMA flash attention. QH/KH: [B,H,T,DH] ; VT: [B,H,DH,T] ; AO: [B,T,H*DH] bf16
// Q pre-scaled by 0.125*log2e -> p = exp2(S). Interior tiles skip masking.
// r4: softmax denominator via MFMA(pf, ones) on the idle matrix pipe (r3 PMC:
// VALUBusy 62% vs MfmaUtil 18% -> VALU-issue-bound). Deletes the 12 per-tile
// lpart adds + the whole epilogue shuffle reduction: lsum's C-layout row
// (quad*4+r) matches O's row layout, so 1/l is per-lane local.
__global__ __launch_bounds__(256) void attn_mfma_kernel(const unsigned short* __restrict__ QH,
                                                        const unsigned short* __restrict__ KH,
                                                        const unsigned short* __restrict__ VT,
                                                        unsigned short* __restrict__ AO) {
  __shared__ __align__(16) unsigned short kls[64 * 64];     // [s][d], chunk^=s&7
  __shared__ __align__(16) unsigned short vls[64 * 64];     // [d][s], chunk^=d&7
  __shared__ __align__(16) unsigned short pls[4 * 16 * 40]; // per wave [q][32k + pad]

  int w = threadIdx.x >> 6, lane = threadIdx.x & 63;
  int quad = lane >> 4, mr = lane & 15;
  int m7 = mr & 7;
  int bh = blockIdx.x & 63;            // qb-major: heavy tiles dispatch first;
  int qb = 31 - (blockIdx.x >> 6);     // fixed bh stays on one XCD (ids differ by 64)
  int q0 = qb * 64;
  int b = bh >> 4, h = bh & 15;

  const unsigned short* kbase = KH + (long)bh * TT * DHH;
  const unsigned short* vtb  = VT + (long)bh * DHH * TT;
  const unsigned short* qbp  = QH + (long)bh * TT * DHH;

  // Q fragments (MFMA B-operand for S^T): q = q0 + w*16 + mr
  bf16x8 qf[2];
#pragma unroll
  for (int kd = 0; kd < 2; ++kd)
    qf[kd] = *(const bf16x8*)(qbp + (long)(q0 + w * 16 + mr) * DHH + kd * 32 + quad * 8);

  bf16x8 vone;                         // 1.0 bf16 broadcast (denominator MFMA B-op)
#pragma unroll
  for (int i = 0; i < 8; ++i) vone[i] = (short)0x3F80;

  int srow = lane >> 3, schunk = lane & 7;
  const unsigned short* kgp = kbase + (long)(w * 16 + srow) * DHH + ((schunk ^ srow) << 3);
  const unsigned short* vgp = vtb + (long)(w * 16 + srow) * TT + ((schunk ^ srow) << 3);
  unsigned short* klu = kls + w * 16 * 64;
  unsigned short* vlu = vls + w * 16 * 64;

  f32x4 O[4] = {};     // [nd]  row=quad*4+r (q), col=mr (d)
  f32x4 lsum = {};     // softmax denominators, row=quad*4+r (q), all cols equal
  unsigned short* pw = pls + w * 16 * 40;
  int qmin = q0 + w * 16;
  int qcol = qmin + mr;

  for (int s0 = 0; s0 < q0 + 64; s0 += 64) {
    __syncthreads();
    gload16(kgp + (long)s0 * DHH, klu);
    gload16(kgp + (long)s0 * DHH + 8 * DHH, klu + 8 * 64);
    gload16(vgp + s0, vlu);
    gload16(vgp + s0 + 8 * TT, vlu + 8 * 64);
    __syncthreads();

#pragma unroll
    for (int sk = 0; sk < 2; ++sk) {
      int kt0 = s0 + sk * 32;
      if (kt0 > qmin + 15) continue;         // wave-uniform skip
      bool full = (kt0 + 31 <= qmin);        // wave-uniform: no mask needed
#pragma unroll
      for (int nh = 0; nh < 2; ++nh) {
        int ns = sk * 2 + nh;
        int krow = ns * 16 + mr;
        int p0 = quad ^ m7;
        bf16x8 kf0 = *(const bf16x8*)&kls[krow * 64 + p0 * 8];
        bf16x8 kf1 = *(const bf16x8*)&kls[krow * 64 + (p0 ^ 4) * 8];
        f32x4 acc = {};
        acc = MFMA(kf0, qf[0], acc);
        acc = MFMA(kf1, qf[1], acc);
        float pe0, pe1, pe2, pe3;
        if (full) {
          pe0 = __builtin_amdgcn_exp2f(acc[0]);
          pe1 = __builtin_amdgcn_exp2f(acc[1]);
          pe2 = __builtin_amdgcn_exp2f(acc[2]);
          pe3 = __builtin_amdgcn_exp2f(acc[3]);
        } else {
          int sbase = s0 + ns * 16 + quad * 4;
          pe0 = (sbase + 0 <= qcol) ? __builtin_amdgcn_exp2f(acc[0]) : 0.f;
          pe1 = (sbase + 1 <= qcol) ? __builtin_amdgcn_exp2f(acc[1]) : 0.f;
          pe2 = (sbase + 2 <= qcol) ? __builtin_amdgcn_exp2f(acc[2]) : 0.f;
          pe3 = (sbase + 3 <= qcol) ? __builtin_amdgcn_exp2f(acc[3]) : 0.f;
        }
        u32x2 pk;
        pk[0] = pack2bf(pe0, pe1);
        pk[1] = pack2bf(pe2, pe3);
        *(u32x2*)&pw[mr * 40 + nh * 16 + quad * 4] = pk;
      }
      // --- O += P V ; denominators += P·1  (same-wave LDS, no barrier) ---
      bf16x8 pf = *(const bf16x8*)&pw[mr * 40 + quad * 8];
      lsum = MFMA(pf, vone, lsum);
      int pv = (sk * 4 + quad) ^ m7;
#pragma unroll
      for (int nd = 0; nd < 4; ++nd) {
        bf16x8 vf = *(const bf16x8*)&vls[(nd * 16 + mr) * 64 + pv * 8];
        O[nd] = MFMA(pf, vf, O[nd]);
      }
    }
  }

  // lsum[r] = full row denominator for q = qmin + quad*4 + r (lane-local).
#pragma unroll
  for (int r = 0; r < 4; ++r) {
    float rlr = __builtin_amdgcn_rcpf(lsum[r]);
    int t = q0 + w * 16 + quad * 4 + r;
    unsigned short* orow = AO + ((long)(b * TT + t)) * (HH * DHH) + h * DHH + mr;
#pragma unroll
    for (int nd = 0; nd < 4; ++nd)
      orow[nd * 16] = f2bf(O[nd][r] * rlr);
  }
}

extern "C" void kernel_launch(void* const* d_in, const int* in_sizes, int n_in,
                              void* d_out, int out_size, void* d_ws, size_t ws_size,
                              hipStream_t stream) {
  const float* k  = (const float*)d_in[0];
  const float* q  = (const float*)d_in[1];
  const float* v  = (const float*)d_in[2];
  const float* Wk = (const float*)d_in[3];
  const float* Wq = (const float*)d_in[4];
  const float* Wv = (const float*)d_in[5];
  const float* Wo = (const float*)d_in[6];
  const float* bo = (const float*)d_in[7];
  float* out = (float*)d_out;

  const size_t PROJ = (size_t)BB * HH * TT * DHH;  // 8.39M elems
  const size_t WSZ  = (size_t)HH * DHH * CC;       // 1.05M elems
  unsigned short* qh  = (unsigned short*)d_ws;
  unsigned short* kh  = qh + PROJ;
  unsigned short* vh  = kh + PROJ;                 // [B,H,DH,T] (transposed)
  unsigned short* WqT = vh + PROJ;
  unsigned short* WkT = WqT + WSZ;
  unsigned short* WvT = WkT + WSZ;
  unsigned short* WoT = WvT + WSZ;
  unsigned short* AO  = WoT + WSZ;                 // B*T*1024 bf16
  unsigned short* Xq  = AO;                        // alias: dead before attn writes AO
  unsigned short* Xk  = (unsigned short*)out;      // d_out doubles as bf16 scratch
  unsigned short* Xv  = Xk + PROJ;                 // (fully overwritten by oproj later)

  convAll_kernel<<<25600, 256, 0, stream>>>(q, k, v, Wq, Wk, Wv, Wo,
                                            Xq, Xk, Xv, WqT, WkT, WvT, WoT);
  proj3_kernel<<<1536, 256, 0, stream>>>(Xq, Xk, Xv, WqT, WkT, WvT, qh, kh, vh);
  attn_mfma_kernel<<<BB * HH * (TT / 64), 256, 0, stream>>>(qh, kh, vh, AO);
  oproj_kernel<<<512, 256, 0, stream>>>(AO, WoT, bo, out);
}